// Round 1
// baseline (63.208 us; speedup 1.0000x reference)
//
#include <hip/hip_runtime.h>
#include <math.h>

#define D 2048
#define NROWS 8192      // B*T = 4*2048
#define NBUF 512
#define RC 512          // row chunks in k1 (partial lives in d_out: RC*D*4 = 4 MB)
#define ROWS_PER_CHUNK 16

// tanh-GELU via sigmoid identity: 0.5*x*(1+tanh(a*(x+0.044715 x^3))) = x*sigmoid(2*a*u)
__device__ __forceinline__ float gelu_f(float v) {
    float u = v * (1.0f + 0.044715f * v * v);
    float t = -2.0f * 0.7978845608028654f * u;
    return v / (1.0f + __expf(t));
}

// ---- k1: partial column sums of gelu(x). grid (2, RC), block 256. 1024 blocks = 16 waves/CU.
__global__ __launch_bounds__(256) void k1_colsum(const float* __restrict__ x,
                                                 float* __restrict__ partial) {
    const int cg = blockIdx.x * 256 + threadIdx.x;   // float4 column group [0,512)
    const int r0 = blockIdx.y * ROWS_PER_CHUNK;
    const float4* x4 = (const float4*)x;
    float ax = 0.f, ay = 0.f, az = 0.f, aw = 0.f;
    #pragma unroll 8
    for (int r = 0; r < ROWS_PER_CHUNK; ++r) {
        float4 v = x4[(size_t)(r0 + r) * (D / 4) + cg];
        ax += gelu_f(v.x); ay += gelu_f(v.y); az += gelu_f(v.z); aw += gelu_f(v.w);
    }
    float4 o; o.x = ax; o.y = ay; o.z = az; o.w = aw;
    ((float4*)partial)[(size_t)blockIdx.y * (D / 4) + cg] = o;
}

// ---- k1b: reduce RC partials -> ysum[D]. grid 64, block 256 (32 cols x 8 k-slices).
__global__ __launch_bounds__(256) void k1b_reduce(const float* __restrict__ partial,
                                                  float* __restrict__ ysum,
                                                  unsigned int* __restrict__ counter) {
    const int tid = threadIdx.x;
    if (blockIdx.x == 0 && tid == 0) *counter = 0u;   // arm k2's completion counter
    const int col   = blockIdx.x * 32 + (tid & 31);
    const int slice = tid >> 5;                        // 8 slices of RC/8 k-values
    const int k0 = slice * (RC / 8);
    float s = 0.f;
    #pragma unroll 8
    for (int k = 0; k < RC / 8; ++k) s += partial[(size_t)(k0 + k) * D + col];
    __shared__ float red[256];
    red[tid] = s;
    __syncthreads();
    if (tid < 32) {
        float t = red[tid];
        #pragma unroll
        for (int j = 1; j < 8; ++j) t += red[j * 32 + tid];
        ysum[blockIdx.x * 32 + tid] = t;
    }
}

// ---- k2: per-buf-row dot+norm2 (block NBUF does ||ysum||^2), then the LAST block
//      to finish runs the selection (old k3) via decoupled last-block-done. grid NBUF+1.
__global__ __launch_bounds__(256) void k2_sims_select(
        const float* __restrict__ buf, const float* __restrict__ ysum,
        float* __restrict__ dotv, float* __restrict__ bn2, float* __restrict__ yn2,
        const int* __restrict__ mask, const float* __restrict__ inj,
        const float* __restrict__ log_inject, const float* __restrict__ xbuf,
        const float* __restrict__ xglobal, float* __restrict__ scal,
        unsigned int* __restrict__ counter) {
    const int tid = threadIdx.x;
    const int b = blockIdx.x;
    float dacc = 0.f, nacc = 0.f;
    const float4* y4 = (const float4*)ysum;
    if (b < NBUF) {
        const float4* b4 = (const float4*)(buf + (size_t)b * D);
        for (int c = tid; c < D / 4; c += 256) {
            float4 bv = b4[c]; float4 yv = y4[c];
            dacc += bv.x * yv.x + bv.y * yv.y + bv.z * yv.z + bv.w * yv.w;
            nacc += bv.x * bv.x + bv.y * bv.y + bv.z * bv.z + bv.w * bv.w;
        }
    } else {
        for (int c = tid; c < D / 4; c += 256) {
            float4 yv = y4[c];
            dacc += yv.x * yv.x + yv.y * yv.y + yv.z * yv.z + yv.w * yv.w;
        }
    }
    #pragma unroll
    for (int off = 32; off; off >>= 1) {
        dacc += __shfl_down(dacc, off, 64);
        nacc += __shfl_down(nacc, off, 64);
    }
    __shared__ float sa[4], sb[4];
    const int lane = tid & 63, w = tid >> 6;
    if (lane == 0) { sa[w] = dacc; sb[w] = nacc; }
    __syncthreads();
    if (tid == 0) {
        float dt = sa[0] + sa[1] + sa[2] + sa[3];
        float nt = sb[0] + sb[1] + sb[2] + sb[3];
        if (b < NBUF) { dotv[b] = dt; bn2[b] = nt; }
        else yn2[0] = dt;
    }

    // ---- completion check: last block through runs the selection
    __shared__ int s_done;
    if (tid == 0) {
        __threadfence();                               // release our dotv/bn2/yn2 stores
        unsigned int o = atomicAdd(counter, 1u);
        s_done = (o == (unsigned)NBUF);                // 513 blocks -> last sees old==512
    }
    __syncthreads();
    if (!s_done) return;
    __threadfence();                                   // acquire all blocks' stores

    // ---- selection (old k3): sims + argmax + inj_level + nudge/stored norms
    __shared__ float sv[256];
    __shared__ int   si[256];
    const float nm = fmaxf(sqrtf(yn2[0]) * (1.0f / 8192.0f), 1e-12f);
    float bestv = -INFINITY; int besti = 1 << 30;
    for (int i = tid; i < NBUF; i += 256) {
        float nb = fmaxf(sqrtf(bn2[i]), 1e-12f);
        float sim = (dotv[i] * (1.0f / 8192.0f)) / (nm * nb);
        if (!mask[i]) sim = -1.0f;
        if (sim > bestv || (sim == bestv && i < besti)) { bestv = sim; besti = i; }
    }
    sv[tid] = bestv; si[tid] = besti;
    __syncthreads();
    for (int s = 128; s; s >>= 1) {
        if (tid < s) {
            float v2 = sv[tid + s]; int i2 = si[tid + s];
            if (v2 > sv[tid] || (v2 == sv[tid] && i2 < si[tid])) { sv[tid] = v2; si[tid] = i2; }
        }
        __syncthreads();
    }
    __shared__ int s_idx;
    __shared__ float s_lvl;
    if (tid == 0) {
        int idx = si[0];
        float max_sim = sv[0];
        float ib = fminf(fmaxf(__expf(log_inject[0]), 0.001f), 2.0f);
        float inear = inj[idx];
        float lvl = (max_sim > 0.85f) ? ((inear < 1e-6f) ? ib : inear * 2.0f) : inear;
        s_idx = idx; s_lvl = lvl;
    }
    __syncthreads();
    const int idx = s_idx;
    float n2 = 0.f, s2 = 0.f;
    const float* sr = xbuf + (size_t)idx * D;
    for (int d = tid; d < D; d += 256) {
        float sx = sr[d];
        float nd = sx - xglobal[d];
        n2 += nd * nd; s2 += sx * sx;
    }
    #pragma unroll
    for (int off = 32; off; off >>= 1) {
        n2 += __shfl_down(n2, off, 64);
        s2 += __shfl_down(s2, off, 64);
    }
    __shared__ float ra[4], rb[4];
    if (lane == 0) { ra[w] = n2; rb[w] = s2; }
    __syncthreads();
    if (tid == 0) {
        float nt = ra[0] + ra[1] + ra[2] + ra[3];
        float st = rb[0] + rb[1] + rb[2] + rb[3];
        scal[0] = s_lvl;                                  // inj_level
        scal[1] = 1.0f / fmaxf(sqrtf(nt), 1e-6f);         // 1/||nudge_dir||
        scal[2] = 1.0f / fmaxf(sqrtf(st), 1e-12f);        // 1/||stored_x||
        ((int*)scal)[3] = idx;                            // nearest_idx
    }
}

// ---- k4: per-token row: tok_sim + gelu(x + c*(s-g)). grid NROWS, block 256.
__global__ __launch_bounds__(256) void k4_out(const float* __restrict__ x,
                                              const float* __restrict__ xbuf,
                                              const float* __restrict__ xglobal,
                                              const float* __restrict__ scal,
                                              float* __restrict__ out) {
    const int tid = threadIdx.x;
    const size_t row = blockIdx.x;
    const float inj_level = scal[0];
    const float rnudge = scal[1];
    const float rstored = scal[2];
    const int idx = ((const int*)scal)[3];

    const float4* xr = (const float4*)(x + row * D);
    const float4* sr = (const float4*)(xbuf + (size_t)idx * D);
    const float4* gr = (const float4*)xglobal;

    float4 x0 = xr[tid], x1 = xr[tid + 256];
    float4 s0 = sr[tid], s1 = sr[tid + 256];
    float4 g0 = gr[tid], g1 = gr[tid + 256];

    float dxs = x0.x * s0.x + x0.y * s0.y + x0.z * s0.z + x0.w * s0.w
              + x1.x * s1.x + x1.y * s1.y + x1.z * s1.z + x1.w * s1.w;
    float dxx = x0.x * x0.x + x0.y * x0.y + x0.z * x0.z + x0.w * x0.w
              + x1.x * x1.x + x1.y * x1.y + x1.z * x1.z + x1.w * x1.w;

    #pragma unroll
    for (int off = 32; off; off >>= 1) {
        dxs += __shfl_down(dxs, off, 64);
        dxx += __shfl_down(dxx, off, 64);
    }
    __shared__ float sa[4], sb[4];
    const int lane = tid & 63, w = tid >> 6;
    if (lane == 0) { sa[w] = dxs; sb[w] = dxx; }
    __syncthreads();
    __shared__ float s_coef;
    if (tid == 0) {
        float dt = sa[0] + sa[1] + sa[2] + sa[3];
        float nt = sb[0] + sb[1] + sb[2] + sb[3];
        float rx = 1.0f / fmaxf(sqrtf(nt), 1e-12f);
        float ts = fminf(fmaxf(dt * rx * rstored, 0.0f), 1.0f);  // tok_sim
        s_coef = (inj_level < 1e-6f) ? 0.0f : inj_level * ts * rnudge;
    }
    __syncthreads();
    const float c = s_coef;

    float4 o0, o1;
    o0.x = gelu_f(x0.x + c * (s0.x - g0.x));
    o0.y = gelu_f(x0.y + c * (s0.y - g0.y));
    o0.z = gelu_f(x0.z + c * (s0.z - g0.z));
    o0.w = gelu_f(x0.w + c * (s0.w - g0.w));
    o1.x = gelu_f(x1.x + c * (s1.x - g1.x));
    o1.y = gelu_f(x1.y + c * (s1.y - g1.y));
    o1.z = gelu_f(x1.z + c * (s1.z - g1.z));
    o1.w = gelu_f(x1.w + c * (s1.w - g1.w));

    float4* orow = (float4*)(out + row * D);
    orow[tid] = o0; orow[tid + 256] = o1;
}

extern "C" void kernel_launch(void* const* d_in, const int* in_sizes, int n_in,
                              void* d_out, int out_size, void* d_ws, size_t ws_size,
                              hipStream_t stream) {
    const float* x          = (const float*)d_in[0];
    const float* log_inject = (const float*)d_in[1];
    const float* buf        = (const float*)d_in[2];
    const float* xbuf       = (const float*)d_in[3];
    const float* inj        = (const float*)d_in[4];
    const float* xglobal    = (const float*)d_in[5];
    const int*   mask       = (const int*)d_in[6];
    float* out = (float*)d_out;
    float* ws  = (float*)d_ws;

    float* ysum    = ws;                               // [2048]
    float* dotv    = ws + 2048;                        // [512]
    float* bn2     = ws + 2560;                        // [512]
    float* yn2     = ws + 3072;                        // [1]
    float* scal    = ws + 3076;                        // [4]
    unsigned int* counter = (unsigned int*)(ws + 3080);// [1]

    // partial [RC][D] = 4 MB lives in d_out — consumed by k1b before k4 overwrites out.
    float* partial = out;

    k1_colsum<<<dim3(2, RC), 256, 0, stream>>>(x, partial);
    k1b_reduce<<<64, 256, 0, stream>>>(partial, ysum, counter);
    k2_sims_select<<<NBUF + 1, 256, 0, stream>>>(buf, ysum, dotv, bn2, yn2,
                                                 mask, inj, log_inject,
                                                 xbuf, xglobal, scal, counter);
    k4_out<<<NROWS, 256, 0, stream>>>(x, xbuf, xglobal, scal, out);
}